// Round 8
// baseline (3088.908 us; speedup 1.0000x reference)
//
#include <hip/hip_runtime.h>
#include <hip/hip_bf16.h>

typedef unsigned short u16;
typedef unsigned int u32;
typedef __attribute__((ext_vector_type(8))) __bf16 bf16x8;
typedef __attribute__((ext_vector_type(4))) float f32x4;

#define N_NODES 50000
#define N_EDGES 800000

// ws layout (bytes)
#define OFF_AGG    0            // float[50000*128] = 25,600,000 B
#define OFF_FEATB  25600000     // u16[6,400,000]   = 12,800,000 B
#define OFF_IDX    38400000     // int[1,600,000]   =  6,400,000 B
#define OFF_FLAG   44800000     // int[1]
#define OFF_W1P    44800256     // u16[32768] = 65536 B  (Wm1 rows 0..255 packed)
#define OFF_W2P    44865792     // u16[16384] = 32768 B
#define OFF_WC1P   44898560     // u16[16384] = 32768 B
#define OFF_WFP    44931328     // u16[32768] = 65536 B

#define MFMA(a,b,c) __builtin_amdgcn_mfma_f32_16x16x32_bf16((a),(b),(c),0,0,0)

__device__ __forceinline__ u16 f2bf(float f) {
    u32 u = __float_as_uint(f);
    u32 r = u + 0x7fffu + ((u >> 16) & 1u);   // RNE; inputs are finite
    return (u16)(r >> 16);
}

__device__ __forceinline__ float bf2f(u16 h) {
    return __uint_as_float(((u32)h) << 16);
}

__device__ __forceinline__ float fsilu(float x) {
    return x / (1.0f + __expf(-x));
}

// ---------------------------------------------------------------------------
// Kernel 0: detect whether edge_index arrived as int64 (odd 32-bit words == 0)
// ---------------------------------------------------------------------------
__global__ void detect_k(const int* __restrict__ ei, int* __restrict__ flag) {
    int v = ei[2 * threadIdx.x + 1];
    unsigned long long nz = __ballot(v != 0);
    if (threadIdx.x == 0) flag[0] = (nz == 0ULL) ? 1 : 0;
}

// ---------------------------------------------------------------------------
// Weight packing: Wp[((ks*8+nt)*64+lane)*8 + j] = bf16(W[(ks*32+(lane>>4)*8+j)][nt*16+(lane&15)])
// One wave B-fragment load = one coalesced global_load_dwordx4.
// ---------------------------------------------------------------------------
__device__ __forceinline__ void pack_w(const float* __restrict__ W, u16* __restrict__ Wp, int g) {
    const int lane = g & 63;
    const int nt   = (g >> 6) & 7;
    const int ks   = g >> 9;
    const int k0   = ks * 32 + (lane >> 4) * 8;
    const int col  = nt * 16 + (lane & 15);
    u32 p[4];
#pragma unroll
    for (int jj = 0; jj < 4; ++jj) {
        u16 lo = f2bf(W[(k0 + 2 * jj    ) * 128 + col]);
        u16 hi = f2bf(W[(k0 + 2 * jj + 1) * 128 + col]);
        p[jj] = (u32)lo | ((u32)hi << 16);
    }
    uint4 v = make_uint4(p[0], p[1], p[2], p[3]);
    *reinterpret_cast<uint4*>(Wp + (size_t)g * 8) = v;
}

// ---------------------------------------------------------------------------
// Kernel 1: prep — feat->bf16, agg zero, coords->out, idx normalize, pack weights
// ---------------------------------------------------------------------------
__global__ void prep_k(const float* __restrict__ feat, const float* __restrict__ coords,
                       const int* __restrict__ ei, const int* __restrict__ flag,
                       const float* __restrict__ Wm1, const float* __restrict__ Wm2,
                       const float* __restrict__ Wc1, const float* __restrict__ Wf,
                       u16* __restrict__ featb, float* __restrict__ agg, int* __restrict__ idxw,
                       u16* __restrict__ w1p, u16* __restrict__ w2p,
                       u16* __restrict__ wc1p, u16* __restrict__ wfp,
                       float* __restrict__ outc)
{
    const int R0 = 800000;            // feature 8-float chunks
    const int R1 = R0 + 1600000;      // agg float4 zero
    const int R2 = R1 + 37500;        // coords float4 copy
    const int R3 = R2 + 1600000;      // idx normalize
    const int R4 = R3 + 4096;         // Wm1 pack
    const int R5 = R4 + 2048;         // Wm2 pack
    const int R6 = R5 + 2048;         // Wc1 pack
    const int R7 = R6 + 4096;         // Wf pack
    const int fl = flag[0];
    for (int i = blockIdx.x * blockDim.x + threadIdx.x; i < R7; i += gridDim.x * blockDim.x) {
        if (i < R0) {
            const float4 a = reinterpret_cast<const float4*>(feat)[2 * i];
            const float4 b = reinterpret_cast<const float4*>(feat)[2 * i + 1];
            uint4 v;
            v.x = (u32)f2bf(a.x) | ((u32)f2bf(a.y) << 16);
            v.y = (u32)f2bf(a.z) | ((u32)f2bf(a.w) << 16);
            v.z = (u32)f2bf(b.x) | ((u32)f2bf(b.y) << 16);
            v.w = (u32)f2bf(b.z) | ((u32)f2bf(b.w) << 16);
            reinterpret_cast<uint4*>(featb)[i] = v;
        } else if (i < R1) {
            reinterpret_cast<float4*>(agg)[i - R0] = make_float4(0.f, 0.f, 0.f, 0.f);
        } else if (i < R2) {
            reinterpret_cast<float4*>(outc)[i - R1] = reinterpret_cast<const float4*>(coords)[i - R1];
        } else if (i < R3) {
            const int e = i - R2;
            idxw[e] = fl ? ei[2 * e] : ei[e];
        } else if (i < R4) { pack_w(Wm1, w1p, i - R3); }
        else if (i < R5)   { pack_w(Wm2, w2p, i - R4); }
        else if (i < R6)   { pack_w(Wc1, wc1p, i - R5); }
        else               { pack_w(Wf,  wfp, i - R6); }
    }
}

// ---------------------------------------------------------------------------
// Kernel 2 (R5 rewrite): fused edge MLP, BARRIER-FREE.
// 256 threads = 4 independent waves; wave w owns 16 edges (M=16) and all
// 128 output cols (8 n-tiles). All GEMM A-operands are wave-private, so the
// three __syncthreads() are gone; transposes go through per-wave LDS with
// an lgkmcnt(0) fence. LDS 33 KB -> 4 blocks/CU.
// ---------------------------------------------------------------------------
__global__ __launch_bounds__(256, 4)
void edge_k(const u16* __restrict__ featb, const float* __restrict__ coords,
            const int* __restrict__ idxw,
            const u16* __restrict__ w1p, const u16* __restrict__ w2p, const u16* __restrict__ wc1p,
            const float* __restrict__ Wm1f, const float* __restrict__ bm1,
            const float* __restrict__ bm2, const float* __restrict__ bc1,
            const float* __restrict__ wc2, const float* __restrict__ bc2,
            float* __restrict__ agg, float* __restrict__ outc)
{
    __shared__ u16  sX[4][4096];      // per-wave X tile [16][256]; h [16][128] aliases
                                      // first half, msg [16][128] second half
    __shared__ int   sRow[4][16];
    __shared__ float sDiff[4][48];
    __shared__ float sDist[4][16];

    const int tid  = threadIdx.x;
    const int lane = tid & 63;
    const int w    = tid >> 6;
    const int lhi  = lane >> 4, llo = lane & 15;
    const int e0   = blockIdx.x * 64 + w * 16;   // this wave's first edge

    u16* mysX = sX[w];
    u16* mysH = mysX;                 // alias: sX dead after GEMM1 A-reads
    u16* mysM = mysX + 2048;          // alias: second half of sX

    // ---- per-wave staging: edge meta (lanes 0-15) ----
    if (lane < 16) {
        const int e = e0 + lane;
        const int r = idxw[e];
        const int c = idxw[N_EDGES + e];
        sRow[w][lane] = r;
        const float dx = coords[r * 3 + 0] - coords[c * 3 + 0];
        const float dy = coords[r * 3 + 1] - coords[c * 3 + 1];
        const float dz = coords[r * 3 + 2] - coords[c * 3 + 2];
        sDiff[w][lane * 3 + 0] = dx; sDiff[w][lane * 3 + 1] = dy; sDiff[w][lane * 3 + 2] = dz;
        sDist[w][lane] = dx * dx + dy * dy + dz * dz;
    }
    // ---- per-wave staging: X tile (two-phase gather) ----
    {
        const int ch   = lane & 31;          // chunk within row (0..31), fixed per lane
        const int c    = lane & 15;          // feature chunk (0..15)
        const int part = (lane >> 4) & 1;    // 0: feat[row], 1: feat[col]
        int nodes[8];
#pragma unroll
        for (int it = 0; it < 8; ++it)
            nodes[it] = idxw[part * N_EDGES + e0 + it * 2 + (lane >> 5)];
#pragma unroll
        for (int it = 0; it < 8; ++it) {
            const int e = it * 2 + (lane >> 5);
            const uint4 v = *reinterpret_cast<const uint4*>(featb + (size_t)nodes[it] * 128 + c * 8);
            *reinterpret_cast<uint4*>(&mysX[e * 256 + ((ch ^ (e & 7)) << 3)]) = v;
        }
    }
    asm volatile("s_waitcnt lgkmcnt(0)" ::: "memory");
    __builtin_amdgcn_sched_barrier(0);

    const f32x4 fzero = {0.f, 0.f, 0.f, 0.f};

    // ---- GEMM1: h = silu(X @ Wm1 + dist*Wm1[256] + bm1), K=256 ----
    f32x4 acc[8];
#pragma unroll
    for (int nt = 0; nt < 8; ++nt) acc[nt] = fzero;
#pragma unroll
    for (int ks = 0; ks < 8; ++ks) {
        const bf16x8 a = *reinterpret_cast<const bf16x8*>(
            &mysX[llo * 256 + (((ks * 4 + lhi) ^ (llo & 7)) << 3)]);
#pragma unroll
        for (int nt = 0; nt < 8; ++nt) {
            const bf16x8 b = *reinterpret_cast<const bf16x8*>(
                w1p + (size_t)(((ks * 8 + nt) * 64 + lane) * 8));
            acc[nt] = MFMA(a, b, acc[nt]);
        }
    }
#pragma unroll
    for (int nt = 0; nt < 8; ++nt) {
        const int col = nt * 16 + llo;
        const float wl = Wm1f[256 * 128 + col];   // dist column, fp32
        const float bb = bm1[col];
#pragma unroll
        for (int r = 0; r < 4; ++r) {
            const int row = lhi * 4 + r;
            float v = acc[nt][r] + sDist[w][row] * wl + bb;
            v = fsilu(v);
            mysH[row * 128 + ((((col >> 3) ^ (row & 7)) << 3) | (col & 7))] = f2bf(v);
        }
    }
    asm volatile("s_waitcnt lgkmcnt(0)" ::: "memory");
    __builtin_amdgcn_sched_barrier(0);

    // ---- GEMM2: messages = silu(h @ Wm2 + bm2), K=128 ----
#pragma unroll
    for (int nt = 0; nt < 8; ++nt) acc[nt] = fzero;
#pragma unroll
    for (int ks = 0; ks < 4; ++ks) {
        const bf16x8 a = *reinterpret_cast<const bf16x8*>(
            &mysH[llo * 128 + (((ks * 4 + lhi) ^ (llo & 7)) << 3)]);
#pragma unroll
        for (int nt = 0; nt < 8; ++nt) {
            const bf16x8 b = *reinterpret_cast<const bf16x8*>(
                w2p + (size_t)(((ks * 8 + nt) * 64 + lane) * 8));
            acc[nt] = MFMA(a, b, acc[nt]);
        }
    }
#pragma unroll
    for (int nt = 0; nt < 8; ++nt) {
        const int col = nt * 16 + llo;
        const float bb = bm2[col];
#pragma unroll
        for (int r = 0; r < 4; ++r) {
            const int row = lhi * 4 + r;
            const float v = fsilu(acc[nt][r] + bb);
            mysM[row * 128 + ((((col >> 3) ^ (row & 7)) << 3) | (col & 7))] = f2bf(v);
        }
    }
    asm volatile("s_waitcnt lgkmcnt(0)" ::: "memory");
    __builtin_amdgcn_sched_barrier(0);

    // ---- GEMM3: t = silu(messages @ Wc1 + bc1); cw = t @ Wc2 + bc2 ----
#pragma unroll
    for (int nt = 0; nt < 8; ++nt) acc[nt] = fzero;
#pragma unroll
    for (int ks = 0; ks < 4; ++ks) {
        const bf16x8 a = *reinterpret_cast<const bf16x8*>(
            &mysM[llo * 128 + (((ks * 4 + lhi) ^ (llo & 7)) << 3)]);
#pragma unroll
        for (int nt = 0; nt < 8; ++nt) {
            const bf16x8 b = *reinterpret_cast<const bf16x8*>(
                wc1p + (size_t)(((ks * 8 + nt) * 64 + lane) * 8));
            acc[nt] = MFMA(a, b, acc[nt]);
        }
    }
    float part[4] = {0.f, 0.f, 0.f, 0.f};
#pragma unroll
    for (int nt = 0; nt < 8; ++nt) {
        const int col = nt * 16 + llo;
        const float bb  = bc1[col];
        const float wcv = wc2[col];
#pragma unroll
        for (int r = 0; r < 4; ++r)
            part[r] += fsilu(acc[nt][r] + bb) * wcv;
    }
#pragma unroll
    for (int m = 1; m < 16; m <<= 1) {
#pragma unroll
        for (int r = 0; r < 4; ++r)
            part[r] += __shfl_xor(part[r], m, 64);
    }
    // ---- coord update scatter (lanes llo==0 hold row sums) ----
    if (llo == 0) {
        const float b2 = bc2[0];
#pragma unroll
        for (int r = 0; r < 4; ++r) {
            const int row = lhi * 4 + r;
            const float cwv = part[r] + b2;
            const int rn = sRow[w][row];
            atomicAdd(&outc[rn * 3 + 0], cwv * sDiff[w][row * 3 + 0]);
            atomicAdd(&outc[rn * 3 + 1], cwv * sDiff[w][row * 3 + 1]);
            atomicAdd(&outc[rn * 3 + 2], cwv * sDiff[w][row * 3 + 2]);
        }
    }
    // ---- agg scatter: re-read bf16 msg tile (fire-and-forget atomics) ----
#pragma unroll
    for (int it = 0; it < 4; ++it) {
        const int slot = it * 64 + lane;
        const int e  = slot >> 4;
        const int ch = slot & 15;
        const uint4 v = *reinterpret_cast<const uint4*>(&mysM[e * 128 + ((ch ^ (e & 7)) << 3)]);
        float* dst = &agg[(size_t)sRow[w][e] * 128 + ch * 8];
        atomicAdd(dst + 0, bf2f((u16)(v.x & 0xffffu)));
        atomicAdd(dst + 1, __uint_as_float(v.x & 0xffff0000u));
        atomicAdd(dst + 2, bf2f((u16)(v.y & 0xffffu)));
        atomicAdd(dst + 3, __uint_as_float(v.y & 0xffff0000u));
        atomicAdd(dst + 4, bf2f((u16)(v.z & 0xffffu)));
        atomicAdd(dst + 5, __uint_as_float(v.z & 0xffff0000u));
        atomicAdd(dst + 6, bf2f((u16)(v.w & 0xffffu)));
        atomicAdd(dst + 7, __uint_as_float(v.w & 0xffff0000u));
    }
}

// ---------------------------------------------------------------------------
// Kernel 3: new_features = silu([features, aggregated] @ Wf + bf)
// ---------------------------------------------------------------------------
__global__ __launch_bounds__(256, 2)
void node_k(const u16* __restrict__ featb, const float* __restrict__ agg,
            const u16* __restrict__ wfp, const float* __restrict__ bfv,
            float* __restrict__ out)
{
    __shared__ u16 sA[64 * 256];
    const int tid  = threadIdx.x;
    const int lane = tid & 63;
    const int w    = tid >> 6;
    const int lhi  = lane >> 4, llo = lane & 15;
    const int n0   = blockIdx.x * 64;

    {
        const int c = tid & 15;
        for (int pr = tid >> 4; pr < 128; pr += 16) {
            const int nl = pr >> 1, part = pr & 1;
            const int node = n0 + nl;
            uint4 v = make_uint4(0u, 0u, 0u, 0u);
            if (node < N_NODES) {
                if (part == 0) {
                    v = *reinterpret_cast<const uint4*>(featb + node * 128 + c * 8);
                } else {
                    const float4 a = reinterpret_cast<const float4*>(agg + node * 128)[2 * c];
                    const float4 b = reinterpret_cast<const float4*>(agg + node * 128)[2 * c + 1];
                    v.x = (u32)f2bf(a.x) | ((u32)f2bf(a.y) << 16);
                    v.y = (u32)f2bf(a.z) | ((u32)f2bf(a.w) << 16);
                    v.z = (u32)f2bf(b.x) | ((u32)f2bf(b.y) << 16);
                    v.w = (u32)f2bf(b.z) | ((u32)f2bf(b.w) << 16);
                }
            }
            const int ch = part * 16 + c;
            *reinterpret_cast<uint4*>(&sA[nl * 256 + ((ch ^ (nl & 7)) << 3)]) = v;
        }
    }
    __syncthreads();

    const f32x4 fzero = {0.f, 0.f, 0.f, 0.f};
    f32x4 acc[4][2];
#pragma unroll
    for (int mt = 0; mt < 4; ++mt) { acc[mt][0] = fzero; acc[mt][1] = fzero; }
#pragma unroll
    for (int ks = 0; ks < 8; ++ks) {
        const bf16x8 b0 = *reinterpret_cast<const bf16x8*>(wfp + (((ks * 8) + 2 * w + 0) * 64 + lane) * 8);
        const bf16x8 b1 = *reinterpret_cast<const bf16x8*>(wfp + (((ks * 8) + 2 * w + 1) * 64 + lane) * 8);
#pragma unroll
        for (int mt = 0; mt < 4; ++mt) {
            const int row = mt * 16 + llo;
            const int ch  = ks * 4 + lhi;
            const bf16x8 a = *reinterpret_cast<const bf16x8*>(&sA[row * 256 + ((ch ^ (row & 7)) << 3)]);
            acc[mt][0] = MFMA(a, b0, acc[mt][0]);
            acc[mt][1] = MFMA(a, b1, acc[mt][1]);
        }
    }
#pragma unroll
    for (int nl = 0; nl < 2; ++nl) {
        const int col = (2 * w + nl) * 16 + llo;
        const float bb = bfv[col];
#pragma unroll
        for (int mt = 0; mt < 4; ++mt) {
#pragma unroll
            for (int r = 0; r < 4; ++r) {
                const int row = mt * 16 + lhi * 4 + r;
                const int node = n0 + row;
                if (node < N_NODES) {
                    out[node * 128 + col] = fsilu(acc[mt][nl][r] + bb);
                }
            }
        }
    }
}

// ---------------------------------------------------------------------------
extern "C" void kernel_launch(void* const* d_in, const int* in_sizes, int n_in,
                              void* d_out, int out_size, void* d_ws, size_t ws_size,
                              hipStream_t stream)
{
    const float* features = (const float*)d_in[0];
    const float* coords   = (const float*)d_in[1];
    const int*   ei       = (const int*)d_in[2];
    const float* Wm1 = (const float*)d_in[3];
    const float* bm1 = (const float*)d_in[4];
    const float* Wm2 = (const float*)d_in[5];
    const float* bm2 = (const float*)d_in[6];
    const float* Wc1 = (const float*)d_in[7];
    const float* bc1 = (const float*)d_in[8];
    const float* Wc2 = (const float*)d_in[9];
    const float* bc2 = (const float*)d_in[10];
    const float* Wf  = (const float*)d_in[11];
    const float* bfv = (const float*)d_in[12];

    float* out  = (float*)d_out;
    float* outc = out + (size_t)N_NODES * 128;

    char* ws = (char*)d_ws;
    float* agg  = (float*)(ws + OFF_AGG);
    u16* featb  = (u16*)(ws + OFF_FEATB);
    int* idxw   = (int*)(ws + OFF_IDX);
    int* flag   = (int*)(ws + OFF_FLAG);
    u16* w1p    = (u16*)(ws + OFF_W1P);
    u16* w2p    = (u16*)(ws + OFF_W2P);
    u16* wc1p   = (u16*)(ws + OFF_WC1P);
    u16* wfp    = (u16*)(ws + OFF_WFP);

    detect_k<<<1, 64, 0, stream>>>(ei, flag);
    prep_k<<<2048, 256, 0, stream>>>(features, coords, ei, flag, Wm1, Wm2, Wc1, Wf,
                                     featb, agg, idxw, w1p, w2p, wc1p, wfp, outc);
    edge_k<<<N_EDGES / 64, 256, 0, stream>>>(featb, coords, idxw, w1p, w2p, wc1p,
                                             Wm1, bm1, bm2, bc1, Wc2, bc2, agg, outc);
    node_k<<<(N_NODES + 63) / 64, 256, 0, stream>>>(featb, agg, wfp, bfv, out);
}

// Round 10
// 550.437 us; speedup vs baseline: 5.6117x; 5.6117x over previous
//
#include <hip/hip_runtime.h>
#include <hip/hip_bf16.h>

typedef unsigned short u16;
typedef unsigned int u32;
typedef __attribute__((ext_vector_type(8))) __bf16 bf16x8;
typedef __attribute__((ext_vector_type(4))) float f32x4;

#define N_NODES 50000
#define N_EDGES 800000

// ws layout (bytes)
#define OFF_AGG    0            // float[50000*128] = 25,600,000 B
#define OFF_FEATB  25600000     // u16[6,400,000]   = 12,800,000 B
#define OFF_IDX    38400000     // int[1,600,000]   =  6,400,000 B
#define OFF_FLAG   44800000     // int[1]
#define OFF_W1P    44800256     // u16[32768] = 65536 B  (Wm1 rows 0..255 packed)
#define OFF_W2P    44865792     // u16[16384] = 32768 B
#define OFF_WC1P   44898560     // u16[16384] = 32768 B
#define OFF_WFP    44931328     // u16[32768] = 65536 B

#define MFMA(a,b,c) __builtin_amdgcn_mfma_f32_16x16x32_bf16((a),(b),(c),0,0,0)

__device__ __forceinline__ u16 f2bf(float f) {
    u32 u = __float_as_uint(f);
    u32 r = u + 0x7fffu + ((u >> 16) & 1u);   // RNE; inputs are finite
    return (u16)(r >> 16);
}

__device__ __forceinline__ float bf2f(u16 h) {
    return __uint_as_float(((u32)h) << 16);
}

__device__ __forceinline__ float fsilu(float x) {
    return x / (1.0f + __expf(-x));
}

// ---------------------------------------------------------------------------
// Kernel 0: detect whether edge_index arrived as int64 (odd 32-bit words == 0)
// ---------------------------------------------------------------------------
__global__ void detect_k(const int* __restrict__ ei, int* __restrict__ flag) {
    int v = ei[2 * threadIdx.x + 1];
    unsigned long long nz = __ballot(v != 0);
    if (threadIdx.x == 0) flag[0] = (nz == 0ULL) ? 1 : 0;
}

// ---------------------------------------------------------------------------
// Weight packing: Wp[((ks*8+nt)*64+lane)*8 + j] = bf16(W[(ks*32+(lane>>4)*8+j)][nt*16+(lane&15)])
// ---------------------------------------------------------------------------
__device__ __forceinline__ void pack_w(const float* __restrict__ W, u16* __restrict__ Wp, int g) {
    const int lane = g & 63;
    const int nt   = (g >> 6) & 7;
    const int ks   = g >> 9;
    const int k0   = ks * 32 + (lane >> 4) * 8;
    const int col  = nt * 16 + (lane & 15);
    u32 p[4];
#pragma unroll
    for (int jj = 0; jj < 4; ++jj) {
        u16 lo = f2bf(W[(k0 + 2 * jj    ) * 128 + col]);
        u16 hi = f2bf(W[(k0 + 2 * jj + 1) * 128 + col]);
        p[jj] = (u32)lo | ((u32)hi << 16);
    }
    uint4 v = make_uint4(p[0], p[1], p[2], p[3]);
    *reinterpret_cast<uint4*>(Wp + (size_t)g * 8) = v;
}

// ---------------------------------------------------------------------------
// Kernel 1: prep — feat->bf16, agg zero, coords->out, idx normalize, pack weights
// ---------------------------------------------------------------------------
__global__ void prep_k(const float* __restrict__ feat, const float* __restrict__ coords,
                       const int* __restrict__ ei, const int* __restrict__ flag,
                       const float* __restrict__ Wm1, const float* __restrict__ Wm2,
                       const float* __restrict__ Wc1, const float* __restrict__ Wf,
                       u16* __restrict__ featb, float* __restrict__ agg, int* __restrict__ idxw,
                       u16* __restrict__ w1p, u16* __restrict__ w2p,
                       u16* __restrict__ wc1p, u16* __restrict__ wfp,
                       float* __restrict__ outc)
{
    const int R0 = 800000;            // feature 8-float chunks
    const int R1 = R0 + 1600000;      // agg float4 zero
    const int R2 = R1 + 37500;        // coords float4 copy
    const int R3 = R2 + 1600000;      // idx normalize
    const int R4 = R3 + 4096;         // Wm1 pack
    const int R5 = R4 + 2048;         // Wm2 pack
    const int R6 = R5 + 2048;         // Wc1 pack
    const int R7 = R6 + 4096;         // Wf pack
    const int fl = flag[0];
    for (int i = blockIdx.x * blockDim.x + threadIdx.x; i < R7; i += gridDim.x * blockDim.x) {
        if (i < R0) {
            const float4 a = reinterpret_cast<const float4*>(feat)[2 * i];
            const float4 b = reinterpret_cast<const float4*>(feat)[2 * i + 1];
            uint4 v;
            v.x = (u32)f2bf(a.x) | ((u32)f2bf(a.y) << 16);
            v.y = (u32)f2bf(a.z) | ((u32)f2bf(a.w) << 16);
            v.z = (u32)f2bf(b.x) | ((u32)f2bf(b.y) << 16);
            v.w = (u32)f2bf(b.z) | ((u32)f2bf(b.w) << 16);
            reinterpret_cast<uint4*>(featb)[i] = v;
        } else if (i < R1) {
            reinterpret_cast<float4*>(agg)[i - R0] = make_float4(0.f, 0.f, 0.f, 0.f);
        } else if (i < R2) {
            reinterpret_cast<float4*>(outc)[i - R1] = reinterpret_cast<const float4*>(coords)[i - R1];
        } else if (i < R3) {
            const int e = i - R2;
            idxw[e] = fl ? ei[2 * e] : ei[e];
        } else if (i < R4) { pack_w(Wm1, w1p, i - R3); }
        else if (i < R5)   { pack_w(Wm2, w2p, i - R4); }
        else if (i < R6)   { pack_w(Wc1, wc1p, i - R5); }
        else               { pack_w(Wf,  wfp, i - R6); }
    }
}

// ---------------------------------------------------------------------------
// Kernel 2 (R8): barrier-free edge MLP + COALESCED atomic scatters.
// 4 independent waves/block; wave owns 16 edges x 128 cols. R5's regression
// was the scatter: per-lane sequential scalar atomics -> stride-32B within
// each instruction -> no coalescing (33 B HBM write per 4 B atomic). Now each
// agg atomic instruction has 64 lanes writing 64 CONSECUTIVE floats of one
// edge's row (256 B contig), matching R4's ~4 B/atomic traffic.
// ---------------------------------------------------------------------------
__global__ __launch_bounds__(256, 4)
void edge_k(const u16* __restrict__ featb, const float* __restrict__ coords,
            const int* __restrict__ idxw,
            const u16* __restrict__ w1p, const u16* __restrict__ w2p, const u16* __restrict__ wc1p,
            const float* __restrict__ Wm1f, const float* __restrict__ bm1,
            const float* __restrict__ bm2, const float* __restrict__ bc1,
            const float* __restrict__ wc2, const float* __restrict__ bc2,
            float* __restrict__ agg, float* __restrict__ outc)
{
    __shared__ u16  sX[4][4096];      // per-wave X tile [16][256]; h aliases first
                                      // half, msg second half
    __shared__ int   sRow[4][16];
    __shared__ float sDiff[4][48];
    __shared__ float sDist[4][16];
    __shared__ float sCwv[4][16];

    const int tid  = threadIdx.x;
    const int lane = tid & 63;
    const int w    = tid >> 6;
    const int lhi  = lane >> 4, llo = lane & 15;
    const int e0   = blockIdx.x * 64 + w * 16;   // this wave's first edge

    u16* mysX = sX[w];
    u16* mysH = mysX;                 // alias: sX dead after GEMM1 A-reads
    u16* mysM = mysX + 2048;          // alias: second half of sX

    // ---- per-wave staging: edge meta (lanes 0-15) ----
    if (lane < 16) {
        const int e = e0 + lane;
        const int r = idxw[e];
        const int c = idxw[N_EDGES + e];
        sRow[w][lane] = r;
        const float dx = coords[r * 3 + 0] - coords[c * 3 + 0];
        const float dy = coords[r * 3 + 1] - coords[c * 3 + 1];
        const float dz = coords[r * 3 + 2] - coords[c * 3 + 2];
        sDiff[w][lane * 3 + 0] = dx; sDiff[w][lane * 3 + 1] = dy; sDiff[w][lane * 3 + 2] = dz;
        sDist[w][lane] = dx * dx + dy * dy + dz * dz;
    }
    // ---- per-wave staging: X tile (two-phase gather) ----
    {
        const int ch   = lane & 31;          // chunk within row (0..31), fixed per lane
        const int c    = lane & 15;          // feature chunk (0..15)
        const int part = (lane >> 4) & 1;    // 0: feat[row], 1: feat[col]
        int nodes[8];
#pragma unroll
        for (int it = 0; it < 8; ++it)
            nodes[it] = idxw[part * N_EDGES + e0 + it * 2 + (lane >> 5)];
#pragma unroll
        for (int it = 0; it < 8; ++it) {
            const int e = it * 2 + (lane >> 5);
            const uint4 v = *reinterpret_cast<const uint4*>(featb + (size_t)nodes[it] * 128 + c * 8);
            *reinterpret_cast<uint4*>(&mysX[e * 256 + ((ch ^ (e & 7)) << 3)]) = v;
        }
    }
    asm volatile("s_waitcnt lgkmcnt(0)" ::: "memory");
    __builtin_amdgcn_sched_barrier(0);

    const f32x4 fzero = {0.f, 0.f, 0.f, 0.f};

    // ---- GEMM1: h = silu(X @ Wm1 + dist*Wm1[256] + bm1), K=256 ----
    f32x4 acc[8];
#pragma unroll
    for (int nt = 0; nt < 8; ++nt) acc[nt] = fzero;
#pragma unroll
    for (int ks = 0; ks < 8; ++ks) {
        const bf16x8 a = *reinterpret_cast<const bf16x8*>(
            &mysX[llo * 256 + (((ks * 4 + lhi) ^ (llo & 7)) << 3)]);
#pragma unroll
        for (int nt = 0; nt < 8; ++nt) {
            const bf16x8 b = *reinterpret_cast<const bf16x8*>(
                w1p + (size_t)(((ks * 8 + nt) * 64 + lane) * 8));
            acc[nt] = MFMA(a, b, acc[nt]);
        }
    }
#pragma unroll
    for (int nt = 0; nt < 8; ++nt) {
        const int col = nt * 16 + llo;
        const float wl = Wm1f[256 * 128 + col];   // dist column, fp32
        const float bb = bm1[col];
#pragma unroll
        for (int r = 0; r < 4; ++r) {
            const int row = lhi * 4 + r;
            float v = acc[nt][r] + sDist[w][row] * wl + bb;
            v = fsilu(v);
            mysH[row * 128 + ((((col >> 3) ^ (row & 7)) << 3) | (col & 7))] = f2bf(v);
        }
    }
    asm volatile("s_waitcnt lgkmcnt(0)" ::: "memory");
    __builtin_amdgcn_sched_barrier(0);

    // ---- GEMM2: messages = silu(h @ Wm2 + bm2), K=128 ----
#pragma unroll
    for (int nt = 0; nt < 8; ++nt) acc[nt] = fzero;
#pragma unroll
    for (int ks = 0; ks < 4; ++ks) {
        const bf16x8 a = *reinterpret_cast<const bf16x8*>(
            &mysH[llo * 128 + (((ks * 4 + lhi) ^ (llo & 7)) << 3)]);
#pragma unroll
        for (int nt = 0; nt < 8; ++nt) {
            const bf16x8 b = *reinterpret_cast<const bf16x8*>(
                w2p + (size_t)(((ks * 8 + nt) * 64 + lane) * 8));
            acc[nt] = MFMA(a, b, acc[nt]);
        }
    }
#pragma unroll
    for (int nt = 0; nt < 8; ++nt) {
        const int col = nt * 16 + llo;
        const float bb = bm2[col];
#pragma unroll
        for (int r = 0; r < 4; ++r) {
            const int row = lhi * 4 + r;
            const float v = fsilu(acc[nt][r] + bb);
            mysM[row * 128 + ((((col >> 3) ^ (row & 7)) << 3) | (col & 7))] = f2bf(v);
        }
    }
    asm volatile("s_waitcnt lgkmcnt(0)" ::: "memory");
    __builtin_amdgcn_sched_barrier(0);

    // ---- agg scatter: per-edge fully-coalesced atomic instructions.
    //      All 64 lanes write 64 consecutive floats of one edge's agg row.
#pragma unroll
    for (int e = 0; e < 16; ++e) {
        const int rn = sRow[w][e];
#pragma unroll
        for (int half = 0; half < 2; ++half) {
            const int col = half * 64 + lane;
            const int idx = e * 128 + ((((col >> 3) ^ (e & 7)) << 3) | (col & 7));
            atomicAdd(&agg[(size_t)rn * 128 + col], bf2f(mysM[idx]));
        }
    }

    // ---- GEMM3: t = silu(messages @ Wc1 + bc1); cw = t @ Wc2 + bc2 ----
#pragma unroll
    for (int nt = 0; nt < 8; ++nt) acc[nt] = fzero;
#pragma unroll
    for (int ks = 0; ks < 4; ++ks) {
        const bf16x8 a = *reinterpret_cast<const bf16x8*>(
            &mysM[llo * 128 + (((ks * 4 + lhi) ^ (llo & 7)) << 3)]);
#pragma unroll
        for (int nt = 0; nt < 8; ++nt) {
            const bf16x8 b = *reinterpret_cast<const bf16x8*>(
                wc1p + (size_t)(((ks * 8 + nt) * 64 + lane) * 8));
            acc[nt] = MFMA(a, b, acc[nt]);
        }
    }
    float part[4] = {0.f, 0.f, 0.f, 0.f};
#pragma unroll
    for (int nt = 0; nt < 8; ++nt) {
        const int col = nt * 16 + llo;
        const float bb  = bc1[col];
        const float wcv = wc2[col];
#pragma unroll
        for (int r = 0; r < 4; ++r)
            part[r] += fsilu(acc[nt][r] + bb) * wcv;
    }
#pragma unroll
    for (int m = 1; m < 16; m <<= 1) {
#pragma unroll
        for (int r = 0; r < 4; ++r)
            part[r] += __shfl_xor(part[r], m, 64);
    }
    // all 16 lanes of each llo-group hold the full sum; llo==0 stages cw to LDS
    if (llo == 0) {
        const float b2 = bc2[0];
#pragma unroll
        for (int r = 0; r < 4; ++r)
            sCwv[w][lhi * 4 + r] = part[r] + b2;
    }
    asm volatile("s_waitcnt lgkmcnt(0)" ::: "memory");
    __builtin_amdgcn_sched_barrier(0);

    // ---- coord scatter: one 48-lane instruction, 3 consecutive floats/edge ----
    if (lane < 48) {
        const int e    = lane / 3;
        const int comp = lane - e * 3;
        const float cwv = sCwv[w][e];
        atomicAdd(&outc[(size_t)sRow[w][e] * 3 + comp], cwv * sDiff[w][e * 3 + comp]);
    }
}

// ---------------------------------------------------------------------------
// Kernel 3: new_features = silu([features, aggregated] @ Wf + bf)
// ---------------------------------------------------------------------------
__global__ __launch_bounds__(256, 2)
void node_k(const u16* __restrict__ featb, const float* __restrict__ agg,
            const u16* __restrict__ wfp, const float* __restrict__ bfv,
            float* __restrict__ out)
{
    __shared__ u16 sA[64 * 256];
    const int tid  = threadIdx.x;
    const int lane = tid & 63;
    const int w    = tid >> 6;
    const int lhi  = lane >> 4, llo = lane & 15;
    const int n0   = blockIdx.x * 64;

    {
        const int c = tid & 15;
        for (int pr = tid >> 4; pr < 128; pr += 16) {
            const int nl = pr >> 1, part = pr & 1;
            const int node = n0 + nl;
            uint4 v = make_uint4(0u, 0u, 0u, 0u);
            if (node < N_NODES) {
                if (part == 0) {
                    v = *reinterpret_cast<const uint4*>(featb + node * 128 + c * 8);
                } else {
                    const float4 a = reinterpret_cast<const float4*>(agg + node * 128)[2 * c];
                    const float4 b = reinterpret_cast<const float4*>(agg + node * 128)[2 * c + 1];
                    v.x = (u32)f2bf(a.x) | ((u32)f2bf(a.y) << 16);
                    v.y = (u32)f2bf(a.z) | ((u32)f2bf(a.w) << 16);
                    v.z = (u32)f2bf(b.x) | ((u32)f2bf(b.y) << 16);
                    v.w = (u32)f2bf(b.z) | ((u32)f2bf(b.w) << 16);
                }
            }
            const int ch = part * 16 + c;
            *reinterpret_cast<uint4*>(&sA[nl * 256 + ((ch ^ (nl & 7)) << 3)]) = v;
        }
    }
    __syncthreads();

    const f32x4 fzero = {0.f, 0.f, 0.f, 0.f};
    f32x4 acc[4][2];
#pragma unroll
    for (int mt = 0; mt < 4; ++mt) { acc[mt][0] = fzero; acc[mt][1] = fzero; }
#pragma unroll
    for (int ks = 0; ks < 8; ++ks) {
        const bf16x8 b0 = *reinterpret_cast<const bf16x8*>(wfp + (((ks * 8) + 2 * w + 0) * 64 + lane) * 8);
        const bf16x8 b1 = *reinterpret_cast<const bf16x8*>(wfp + (((ks * 8) + 2 * w + 1) * 64 + lane) * 8);
#pragma unroll
        for (int mt = 0; mt < 4; ++mt) {
            const int row = mt * 16 + llo;
            const int ch  = ks * 4 + lhi;
            const bf16x8 a = *reinterpret_cast<const bf16x8*>(&sA[row * 256 + ((ch ^ (row & 7)) << 3)]);
            acc[mt][0] = MFMA(a, b0, acc[mt][0]);
            acc[mt][1] = MFMA(a, b1, acc[mt][1]);
        }
    }
#pragma unroll
    for (int nl = 0; nl < 2; ++nl) {
        const int col = (2 * w + nl) * 16 + llo;
        const float bb = bfv[col];
#pragma unroll
        for (int mt = 0; mt < 4; ++mt) {
#pragma unroll
            for (int r = 0; r < 4; ++r) {
                const int row = mt * 16 + lhi * 4 + r;
                const int node = n0 + row;
                if (node < N_NODES) {
                    out[node * 128 + col] = fsilu(acc[mt][nl][r] + bb);
                }
            }
        }
    }
}

// ---------------------------------------------------------------------------
extern "C" void kernel_launch(void* const* d_in, const int* in_sizes, int n_in,
                              void* d_out, int out_size, void* d_ws, size_t ws_size,
                              hipStream_t stream)
{
    const float* features = (const float*)d_in[0];
    const float* coords   = (const float*)d_in[1];
    const int*   ei       = (const int*)d_in[2];
    const float* Wm1 = (const float*)d_in[3];
    const float* bm1 = (const float*)d_in[4];
    const float* Wm2 = (const float*)d_in[5];
    const float* bm2 = (const float*)d_in[6];
    const float* Wc1 = (const float*)d_in[7];
    const float* bc1 = (const float*)d_in[8];
    const float* Wc2 = (const float*)d_in[9];
    const float* bc2 = (const float*)d_in[10];
    const float* Wf  = (const float*)d_in[11];
    const float* bfv = (const float*)d_in[12];

    float* out  = (float*)d_out;
    float* outc = out + (size_t)N_NODES * 128;

    char* ws = (char*)d_ws;
    float* agg  = (float*)(ws + OFF_AGG);
    u16* featb  = (u16*)(ws + OFF_FEATB);
    int* idxw   = (int*)(ws + OFF_IDX);
    int* flag   = (int*)(ws + OFF_FLAG);
    u16* w1p    = (u16*)(ws + OFF_W1P);
    u16* w2p    = (u16*)(ws + OFF_W2P);
    u16* wc1p   = (u16*)(ws + OFF_WC1P);
    u16* wfp    = (u16*)(ws + OFF_WFP);

    detect_k<<<1, 64, 0, stream>>>(ei, flag);
    prep_k<<<2048, 256, 0, stream>>>(features, coords, ei, flag, Wm1, Wm2, Wc1, Wf,
                                     featb, agg, idxw, w1p, w2p, wc1p, wfp, outc);
    edge_k<<<N_EDGES / 64, 256, 0, stream>>>(featb, coords, idxw, w1p, w2p, wc1p,
                                             Wm1, bm1, bm2, bc1, Wc2, bc2, agg, outc);
    node_k<<<(N_NODES + 63) / 64, 256, 0, stream>>>(featb, agg, wfp, bfv, out);
}

// Round 11
// 549.237 us; speedup vs baseline: 5.6240x; 1.0022x over previous
//
#include <hip/hip_runtime.h>
#include <hip/hip_bf16.h>

typedef unsigned short u16;
typedef unsigned int u32;
typedef __attribute__((ext_vector_type(8))) __bf16 bf16x8;
typedef __attribute__((ext_vector_type(4))) float f32x4;

#define N_NODES 50000
#define N_EDGES 800000

// ws layout (bytes)
#define OFF_AGG    0            // float[50000*128] = 25,600,000 B
#define OFF_FEATB  25600000     // u16[6,400,000]   = 12,800,000 B
#define OFF_IDX    38400000     // int[1,600,000]   =  6,400,000 B
#define OFF_FLAG   44800000     // int[1]
#define OFF_W1P    44800256     // u16[32768] = 65536 B  (Wm1 rows 0..255 packed)
#define OFF_W2P    44865792     // u16[16384] = 32768 B
#define OFF_WC1P   44898560     // u16[16384] = 32768 B
#define OFF_WFP    44931328     // u16[32768] = 65536 B

#define MFMA(a,b,c) __builtin_amdgcn_mfma_f32_16x16x32_bf16((a),(b),(c),0,0,0)

__device__ __forceinline__ u16 f2bf(float f) {
    u32 u = __float_as_uint(f);
    u32 r = u + 0x7fffu + ((u >> 16) & 1u);   // RNE; inputs are finite
    return (u16)(r >> 16);
}

__device__ __forceinline__ float bf2f(u16 h) {
    return __uint_as_float(((u32)h) << 16);
}

__device__ __forceinline__ float fsilu(float x) {
    return x / (1.0f + __expf(-x));
}

// ---------------------------------------------------------------------------
// Kernel 0: detect whether edge_index arrived as int64 (odd 32-bit words == 0)
// ---------------------------------------------------------------------------
__global__ void detect_k(const int* __restrict__ ei, int* __restrict__ flag) {
    int v = ei[2 * threadIdx.x + 1];
    unsigned long long nz = __ballot(v != 0);
    if (threadIdx.x == 0) flag[0] = (nz == 0ULL) ? 1 : 0;
}

// ---------------------------------------------------------------------------
// Weight packing: Wp[((ks*8+nt)*64+lane)*8 + j] = bf16(W[(ks*32+(lane>>4)*8+j)][nt*16+(lane&15)])
// ---------------------------------------------------------------------------
__device__ __forceinline__ void pack_w(const float* __restrict__ W, u16* __restrict__ Wp, int g) {
    const int lane = g & 63;
    const int nt   = (g >> 6) & 7;
    const int ks   = g >> 9;
    const int k0   = ks * 32 + (lane >> 4) * 8;
    const int col  = nt * 16 + (lane & 15);
    u32 p[4];
#pragma unroll
    for (int jj = 0; jj < 4; ++jj) {
        u16 lo = f2bf(W[(k0 + 2 * jj    ) * 128 + col]);
        u16 hi = f2bf(W[(k0 + 2 * jj + 1) * 128 + col]);
        p[jj] = (u32)lo | ((u32)hi << 16);
    }
    uint4 v = make_uint4(p[0], p[1], p[2], p[3]);
    *reinterpret_cast<uint4*>(Wp + (size_t)g * 8) = v;
}

// ---------------------------------------------------------------------------
// Kernel 1: prep — feat->bf16, agg zero, coords->out, idx normalize, pack weights
// ---------------------------------------------------------------------------
__global__ void prep_k(const float* __restrict__ feat, const float* __restrict__ coords,
                       const int* __restrict__ ei, const int* __restrict__ flag,
                       const float* __restrict__ Wm1, const float* __restrict__ Wm2,
                       const float* __restrict__ Wc1, const float* __restrict__ Wf,
                       u16* __restrict__ featb, float* __restrict__ agg, int* __restrict__ idxw,
                       u16* __restrict__ w1p, u16* __restrict__ w2p,
                       u16* __restrict__ wc1p, u16* __restrict__ wfp,
                       float* __restrict__ outc)
{
    const int R0 = 800000;            // feature 8-float chunks
    const int R1 = R0 + 1600000;      // agg float4 zero
    const int R2 = R1 + 37500;        // coords float4 copy
    const int R3 = R2 + 1600000;      // idx normalize
    const int R4 = R3 + 4096;         // Wm1 pack
    const int R5 = R4 + 2048;         // Wm2 pack
    const int R6 = R5 + 2048;         // Wc1 pack
    const int R7 = R6 + 4096;         // Wf pack
    const int fl = flag[0];
    for (int i = blockIdx.x * blockDim.x + threadIdx.x; i < R7; i += gridDim.x * blockDim.x) {
        if (i < R0) {
            const float4 a = reinterpret_cast<const float4*>(feat)[2 * i];
            const float4 b = reinterpret_cast<const float4*>(feat)[2 * i + 1];
            uint4 v;
            v.x = (u32)f2bf(a.x) | ((u32)f2bf(a.y) << 16);
            v.y = (u32)f2bf(a.z) | ((u32)f2bf(a.w) << 16);
            v.z = (u32)f2bf(b.x) | ((u32)f2bf(b.y) << 16);
            v.w = (u32)f2bf(b.z) | ((u32)f2bf(b.w) << 16);
            reinterpret_cast<uint4*>(featb)[i] = v;
        } else if (i < R1) {
            reinterpret_cast<float4*>(agg)[i - R0] = make_float4(0.f, 0.f, 0.f, 0.f);
        } else if (i < R2) {
            reinterpret_cast<float4*>(outc)[i - R1] = reinterpret_cast<const float4*>(coords)[i - R1];
        } else if (i < R3) {
            const int e = i - R2;
            idxw[e] = fl ? ei[2 * e] : ei[e];
        } else if (i < R4) { pack_w(Wm1, w1p, i - R3); }
        else if (i < R5)   { pack_w(Wm2, w2p, i - R4); }
        else if (i < R6)   { pack_w(Wc1, wc1p, i - R5); }
        else               { pack_w(Wf,  wfp, i - R6); }
    }
}

// ---------------------------------------------------------------------------
// Kernel 2 (R11): barrier-free edge MLP; ALL atomics moved to kernel end.
// vmcnt retires IN ORDER on CDNA: in R8 the agg atomics sat between GEMM2
// and GEMM3, so GEMM3's B-fragment loads (younger in the VMEM queue) could
// not be waited on until all 32 atomic RMWs acked (~us/wave mid-kernel
// stall). Terminal atomics are fire-and-forget.
// ---------------------------------------------------------------------------
__global__ __launch_bounds__(256, 4)
void edge_k(const u16* __restrict__ featb, const float* __restrict__ coords,
            const int* __restrict__ idxw,
            const u16* __restrict__ w1p, const u16* __restrict__ w2p, const u16* __restrict__ wc1p,
            const float* __restrict__ Wm1f, const float* __restrict__ bm1,
            const float* __restrict__ bm2, const float* __restrict__ bc1,
            const float* __restrict__ wc2, const float* __restrict__ bc2,
            float* __restrict__ agg, float* __restrict__ outc)
{
    __shared__ u16  sX[4][4096];      // per-wave X tile [16][256]; h aliases first
                                      // half, msg second half
    __shared__ int   sRow[4][16];
    __shared__ float sDiff[4][48];
    __shared__ float sDist[4][16];
    __shared__ float sCwv[4][16];

    const int tid  = threadIdx.x;
    const int lane = tid & 63;
    const int w    = tid >> 6;
    const int lhi  = lane >> 4, llo = lane & 15;
    const int e0   = blockIdx.x * 64 + w * 16;   // this wave's first edge

    u16* mysX = sX[w];
    u16* mysH = mysX;                 // alias: sX dead after GEMM1 A-reads
    u16* mysM = mysX + 2048;          // alias: second half of sX

    // ---- per-wave staging: edge meta (lanes 0-15) ----
    if (lane < 16) {
        const int e = e0 + lane;
        const int r = idxw[e];
        const int c = idxw[N_EDGES + e];
        sRow[w][lane] = r;
        const float dx = coords[r * 3 + 0] - coords[c * 3 + 0];
        const float dy = coords[r * 3 + 1] - coords[c * 3 + 1];
        const float dz = coords[r * 3 + 2] - coords[c * 3 + 2];
        sDiff[w][lane * 3 + 0] = dx; sDiff[w][lane * 3 + 1] = dy; sDiff[w][lane * 3 + 2] = dz;
        sDist[w][lane] = dx * dx + dy * dy + dz * dz;
    }
    // ---- per-wave staging: X tile (two-phase gather) ----
    {
        const int ch   = lane & 31;          // chunk within row (0..31), fixed per lane
        const int c    = lane & 15;          // feature chunk (0..15)
        const int part = (lane >> 4) & 1;    // 0: feat[row], 1: feat[col]
        int nodes[8];
#pragma unroll
        for (int it = 0; it < 8; ++it)
            nodes[it] = idxw[part * N_EDGES + e0 + it * 2 + (lane >> 5)];
#pragma unroll
        for (int it = 0; it < 8; ++it) {
            const int e = it * 2 + (lane >> 5);
            const uint4 v = *reinterpret_cast<const uint4*>(featb + (size_t)nodes[it] * 128 + c * 8);
            *reinterpret_cast<uint4*>(&mysX[e * 256 + ((ch ^ (e & 7)) << 3)]) = v;
        }
    }
    asm volatile("s_waitcnt lgkmcnt(0)" ::: "memory");
    __builtin_amdgcn_sched_barrier(0);

    const f32x4 fzero = {0.f, 0.f, 0.f, 0.f};

    // ---- GEMM1: h = silu(X @ Wm1 + dist*Wm1[256] + bm1), K=256 ----
    f32x4 acc[8];
#pragma unroll
    for (int nt = 0; nt < 8; ++nt) acc[nt] = fzero;
#pragma unroll
    for (int ks = 0; ks < 8; ++ks) {
        const bf16x8 a = *reinterpret_cast<const bf16x8*>(
            &mysX[llo * 256 + (((ks * 4 + lhi) ^ (llo & 7)) << 3)]);
#pragma unroll
        for (int nt = 0; nt < 8; ++nt) {
            const bf16x8 b = *reinterpret_cast<const bf16x8*>(
                w1p + (size_t)(((ks * 8 + nt) * 64 + lane) * 8));
            acc[nt] = MFMA(a, b, acc[nt]);
        }
    }
#pragma unroll
    for (int nt = 0; nt < 8; ++nt) {
        const int col = nt * 16 + llo;
        const float wl = Wm1f[256 * 128 + col];   // dist column, fp32
        const float bb = bm1[col];
#pragma unroll
        for (int r = 0; r < 4; ++r) {
            const int row = lhi * 4 + r;
            float v = acc[nt][r] + sDist[w][row] * wl + bb;
            v = fsilu(v);
            mysH[row * 128 + ((((col >> 3) ^ (row & 7)) << 3) | (col & 7))] = f2bf(v);
        }
    }
    asm volatile("s_waitcnt lgkmcnt(0)" ::: "memory");
    __builtin_amdgcn_sched_barrier(0);

    // ---- GEMM2: messages = silu(h @ Wm2 + bm2), K=128 ----
#pragma unroll
    for (int nt = 0; nt < 8; ++nt) acc[nt] = fzero;
#pragma unroll
    for (int ks = 0; ks < 4; ++ks) {
        const bf16x8 a = *reinterpret_cast<const bf16x8*>(
            &mysH[llo * 128 + (((ks * 4 + lhi) ^ (llo & 7)) << 3)]);
#pragma unroll
        for (int nt = 0; nt < 8; ++nt) {
            const bf16x8 b = *reinterpret_cast<const bf16x8*>(
                w2p + (size_t)(((ks * 8 + nt) * 64 + lane) * 8));
            acc[nt] = MFMA(a, b, acc[nt]);
        }
    }
#pragma unroll
    for (int nt = 0; nt < 8; ++nt) {
        const int col = nt * 16 + llo;
        const float bb = bm2[col];
#pragma unroll
        for (int r = 0; r < 4; ++r) {
            const int row = lhi * 4 + r;
            const float v = fsilu(acc[nt][r] + bb);
            mysM[row * 128 + ((((col >> 3) ^ (row & 7)) << 3) | (col & 7))] = f2bf(v);
        }
    }
    asm volatile("s_waitcnt lgkmcnt(0)" ::: "memory");
    __builtin_amdgcn_sched_barrier(0);

    // ---- GEMM3: t = silu(messages @ Wc1 + bc1); cw = t @ Wc2 + bc2 ----
#pragma unroll
    for (int nt = 0; nt < 8; ++nt) acc[nt] = fzero;
#pragma unroll
    for (int ks = 0; ks < 4; ++ks) {
        const bf16x8 a = *reinterpret_cast<const bf16x8*>(
            &mysM[llo * 128 + (((ks * 4 + lhi) ^ (llo & 7)) << 3)]);
#pragma unroll
        for (int nt = 0; nt < 8; ++nt) {
            const bf16x8 b = *reinterpret_cast<const bf16x8*>(
                wc1p + (size_t)(((ks * 8 + nt) * 64 + lane) * 8));
            acc[nt] = MFMA(a, b, acc[nt]);
        }
    }
    float part[4] = {0.f, 0.f, 0.f, 0.f};
#pragma unroll
    for (int nt = 0; nt < 8; ++nt) {
        const int col = nt * 16 + llo;
        const float bb  = bc1[col];
        const float wcv = wc2[col];
#pragma unroll
        for (int r = 0; r < 4; ++r)
            part[r] += fsilu(acc[nt][r] + bb) * wcv;
    }
#pragma unroll
    for (int m = 1; m < 16; m <<= 1) {
#pragma unroll
        for (int r = 0; r < 4; ++r)
            part[r] += __shfl_xor(part[r], m, 64);
    }
    // all 16 lanes of each llo-group hold the full sum; llo==0 stages cw to LDS
    if (llo == 0) {
        const float b2 = bc2[0];
#pragma unroll
        for (int r = 0; r < 4; ++r)
            sCwv[w][lhi * 4 + r] = part[r] + b2;
    }
    asm volatile("s_waitcnt lgkmcnt(0)" ::: "memory");
    __builtin_amdgcn_sched_barrier(0);

    // ---- TERMINAL scatters: fire-and-forget, nothing waits on these ----
    // coord scatter: one 48-lane instruction, 3 consecutive floats/edge
    if (lane < 48) {
        const int e    = lane / 3;
        const int comp = lane - e * 3;
        const float cwv = sCwv[w][e];
        atomicAdd(&outc[(size_t)sRow[w][e] * 3 + comp], cwv * sDiff[w][e * 3 + comp]);
    }
    // agg scatter: per-edge fully-coalesced atomic instructions
    // (64 lanes -> 64 consecutive floats of one edge's agg row)
#pragma unroll
    for (int e = 0; e < 16; ++e) {
        const int rn = sRow[w][e];
#pragma unroll
        for (int half = 0; half < 2; ++half) {
            const int col = half * 64 + lane;
            const int idx = e * 128 + ((((col >> 3) ^ (e & 7)) << 3) | (col & 7));
            atomicAdd(&agg[(size_t)rn * 128 + col], bf2f(mysM[idx]));
        }
    }
}

// ---------------------------------------------------------------------------
// Kernel 3: new_features = silu([features, aggregated] @ Wf + bf)
// ---------------------------------------------------------------------------
__global__ __launch_bounds__(256, 2)
void node_k(const u16* __restrict__ featb, const float* __restrict__ agg,
            const u16* __restrict__ wfp, const float* __restrict__ bfv,
            float* __restrict__ out)
{
    __shared__ u16 sA[64 * 256];
    const int tid  = threadIdx.x;
    const int lane = tid & 63;
    const int w    = tid >> 6;
    const int lhi  = lane >> 4, llo = lane & 15;
    const int n0   = blockIdx.x * 64;

    {
        const int c = tid & 15;
        for (int pr = tid >> 4; pr < 128; pr += 16) {
            const int nl = pr >> 1, part = pr & 1;
            const int node = n0 + nl;
            uint4 v = make_uint4(0u, 0u, 0u, 0u);
            if (node < N_NODES) {
                if (part == 0) {
                    v = *reinterpret_cast<const uint4*>(featb + node * 128 + c * 8);
                } else {
                    const float4 a = reinterpret_cast<const float4*>(agg + node * 128)[2 * c];
                    const float4 b = reinterpret_cast<const float4*>(agg + node * 128)[2 * c + 1];
                    v.x = (u32)f2bf(a.x) | ((u32)f2bf(a.y) << 16);
                    v.y = (u32)f2bf(a.z) | ((u32)f2bf(a.w) << 16);
                    v.z = (u32)f2bf(b.x) | ((u32)f2bf(b.y) << 16);
                    v.w = (u32)f2bf(b.z) | ((u32)f2bf(b.w) << 16);
                }
            }
            const int ch = part * 16 + c;
            *reinterpret_cast<uint4*>(&sA[nl * 256 + ((ch ^ (nl & 7)) << 3)]) = v;
        }
    }
    __syncthreads();

    const f32x4 fzero = {0.f, 0.f, 0.f, 0.f};
    f32x4 acc[4][2];
#pragma unroll
    for (int mt = 0; mt < 4; ++mt) { acc[mt][0] = fzero; acc[mt][1] = fzero; }
#pragma unroll
    for (int ks = 0; ks < 8; ++ks) {
        const bf16x8 b0 = *reinterpret_cast<const bf16x8*>(wfp + (((ks * 8) + 2 * w + 0) * 64 + lane) * 8);
        const bf16x8 b1 = *reinterpret_cast<const bf16x8*>(wfp + (((ks * 8) + 2 * w + 1) * 64 + lane) * 8);
#pragma unroll
        for (int mt = 0; mt < 4; ++mt) {
            const int row = mt * 16 + llo;
            const int ch  = ks * 4 + lhi;
            const bf16x8 a = *reinterpret_cast<const bf16x8*>(&sA[row * 256 + ((ch ^ (row & 7)) << 3)]);
            acc[mt][0] = MFMA(a, b0, acc[mt][0]);
            acc[mt][1] = MFMA(a, b1, acc[mt][1]);
        }
    }
#pragma unroll
    for (int nl = 0; nl < 2; ++nl) {
        const int col = (2 * w + nl) * 16 + llo;
        const float bb = bfv[col];
#pragma unroll
        for (int mt = 0; mt < 4; ++mt) {
#pragma unroll
            for (int r = 0; r < 4; ++r) {
                const int row = mt * 16 + lhi * 4 + r;
                const int node = n0 + row;
                if (node < N_NODES) {
                    out[node * 128 + col] = fsilu(acc[mt][nl][r] + bb);
                }
            }
        }
    }
}

// ---------------------------------------------------------------------------
extern "C" void kernel_launch(void* const* d_in, const int* in_sizes, int n_in,
                              void* d_out, int out_size, void* d_ws, size_t ws_size,
                              hipStream_t stream)
{
    const float* features = (const float*)d_in[0];
    const float* coords   = (const float*)d_in[1];
    const int*   ei       = (const int*)d_in[2];
    const float* Wm1 = (const float*)d_in[3];
    const float* bm1 = (const float*)d_in[4];
    const float* Wm2 = (const float*)d_in[5];
    const float* bm2 = (const float*)d_in[6];
    const float* Wc1 = (const float*)d_in[7];
    const float* bc1 = (const float*)d_in[8];
    const float* Wc2 = (const float*)d_in[9];
    const float* bc2 = (const float*)d_in[10];
    const float* Wf  = (const float*)d_in[11];
    const float* bfv = (const float*)d_in[12];

    float* out  = (float*)d_out;
    float* outc = out + (size_t)N_NODES * 128;

    char* ws = (char*)d_ws;
    float* agg  = (float*)(ws + OFF_AGG);
    u16* featb  = (u16*)(ws + OFF_FEATB);
    int* idxw   = (int*)(ws + OFF_IDX);
    int* flag   = (int*)(ws + OFF_FLAG);
    u16* w1p    = (u16*)(ws + OFF_W1P);
    u16* w2p    = (u16*)(ws + OFF_W2P);
    u16* wc1p   = (u16*)(ws + OFF_WC1P);
    u16* wfp    = (u16*)(ws + OFF_WFP);

    detect_k<<<1, 64, 0, stream>>>(ei, flag);
    prep_k<<<2048, 256, 0, stream>>>(features, coords, ei, flag, Wm1, Wm2, Wc1, Wf,
                                     featb, agg, idxw, w1p, w2p, wc1p, wfp, outc);
    edge_k<<<N_EDGES / 64, 256, 0, stream>>>(featb, coords, idxw, w1p, w2p, wc1p,
                                             Wm1, bm1, bm2, bc1, Wc2, bc2, agg, outc);
    node_k<<<(N_NODES + 63) / 64, 256, 0, stream>>>(featb, agg, wfp, bfv, out);
}